// Round 7
// baseline (659.898 us; speedup 1.0000x reference)
//
#include <hip/hip_runtime.h>
#include <hip/hip_bf16.h>

#define NIMG 32
#define NPTS 300000
#define NL   64
#define NBOX 256

#define BANDS  2
#define BROWS  128         // NBOX / BANDS
#define CHUNKS 8
#define CHPTS  (NPTS / CHUNKS)   // 37500

__device__ __forceinline__ int rev8(int x) { return (int)(__brev((unsigned)x) >> 24); }

// native LDS float atomic add (ds_add_f32, no return).
__device__ __forceinline__ void lds_fadd(float* p, float v) {
    unsigned off = (unsigned)(uintptr_t)p;
    asm volatile("ds_add_f32 %0, %1" :: "v"(off), "v"(v));
}

// ---------------- zero fill ----------------
__global__ __launch_bounds__(256) void zero_kernel(float4* p, int n4) {
    int i = blockIdx.x * 256 + threadIdx.x;
    if (i < n4) p[i] = make_float4(0.f, 0.f, 0.f, 0.f);
}

// ---------------- Pass 1: deformation + rotate + shift -> interleaved (px,py) ----------------
__global__ __launch_bounds__(256) void project_kernel(
    const float* __restrict__ z_x, const float* __restrict__ z_y,
    const float* __restrict__ z_z, const float* __restrict__ Zb,
    const float* __restrict__ coords,
    const float* __restrict__ R, const float* __restrict__ shifts,
    float2* __restrict__ pairs)
{
    __shared__ float s_z[3][NIMG][NL];   // 24 KB
    __shared__ float s_R[NIMG][9];
    __shared__ float s_sh[NIMG][2];

    int tid = threadIdx.x;
    for (int i = tid; i < NIMG * NL; i += 256) {
        (&s_z[0][0][0])[i] = z_x[i];
        (&s_z[1][0][0])[i] = z_y[i];
        (&s_z[2][0][0])[i] = z_z[i];
    }
    for (int i = tid; i < NIMG * 9; i += 256) (&s_R[0][0])[i] = R[i];
    if (tid < NIMG * 2) (&s_sh[0][0])[tid] = shifts[tid];
    __syncthreads();

    int p = blockIdx.x * 256 + tid;
    if (p >= NPTS) return;

    float4 zr[16];
    const float4* Zr4 = (const float4*)(Zb + (size_t)p * NL);
    #pragma unroll
    for (int i = 0; i < 16; ++i) zr[i] = Zr4[i];

    float cx0 = coords[3 * p + 0];
    float cy0 = coords[3 * p + 1];
    float cz0 = coords[3 * p + 2];

    for (int b = 0; b < NIMG; ++b) {
        const float4* zx4 = (const float4*)s_z[0][b];
        const float4* zy4 = (const float4*)s_z[1][b];
        const float4* zz4 = (const float4*)s_z[2][b];
        float dx = 0.f, dy = 0.f, dz = 0.f;
        #pragma unroll
        for (int i = 0; i < 16; ++i) {
            float4 a = zx4[i];
            dx += a.x * zr[i].x + a.y * zr[i].y + a.z * zr[i].z + a.w * zr[i].w;
            float4 bb = zy4[i];
            dy += bb.x * zr[i].x + bb.y * zr[i].y + bb.z * zr[i].z + bb.w * zr[i].w;
            float4 c = zz4[i];
            dz += c.x * zr[i].x + c.y * zr[i].y + c.z * zr[i].z + c.w * zr[i].w;
        }
        float cx = cx0 + dx, cy = cy0 + dy, cz = cz0 + dz;
        const float* Rb = s_R[b];
        float px = Rb[0] * cx + Rb[1] * cy + Rb[2] * cz + s_sh[b][0] + 128.0f;
        float py = Rb[3] * cx + Rb[4] * cy + Rb[5] * cz + s_sh[b][1] + 128.0f;
        pairs[(size_t)b * NPTS + p] = make_float2(px, py);
    }
}

// ---------------- Pass 2: half-image LDS band splat (branch-free ds_add_f32) ----------------
// Grid: id = img*16 + band*8 + chunk  (band pair of one chunk differs by 8 -> same XCD)
__global__ __launch_bounds__(1024) void splat2_kernel(
    const float2* __restrict__ pairs, const float* __restrict__ weights,
    float* __restrict__ img)
{
    __shared__ float tile[BROWS * NBOX];   // 128 KB
    int tid = threadIdx.x;
    int id = blockIdx.x;
    int b     = id >> 4;
    int band  = (id >> 3) & 1;
    int chunk = id & 7;

    float4* t4 = (float4*)tile;
    for (int i = tid; i < BROWS * NBOX / 4; i += 1024)
        t4[i] = make_float4(0.f, 0.f, 0.f, 0.f);
    __syncthreads();

    const int y_lo = band * BROWS;
    const float2* pp = pairs + (size_t)b * NPTS + (size_t)chunk * CHPTS;
    const float*  wp = weights + (size_t)chunk * CHPTS;

    for (int i = 4 * tid; i < CHPTS; i += 4096) {
        float4 q0 = *(const float4*)(pp + i);       // points i, i+1
        float4 q1 = *(const float4*)(pp + i + 2);   // points i+2, i+3
        float4 wv = *(const float4*)(wp + i);
        float pxa[4] = {q0.x, q0.z, q1.x, q1.z};
        float pya[4] = {q0.y, q0.w, q1.y, q1.w};
        float wa[4]  = {wv.x, wv.y, wv.z, wv.w};
        #pragma unroll
        for (int k = 0; k < 4; ++k) {
            float px = pxa[k], py = pya[k], w = wa[k];
            float x0 = floorf(px), y0 = floorf(py);
            float fx = px - x0, fy = py - y0;
            int xi0 = min(max((int)x0, 0), NBOX - 1);
            int yi0 = min(max((int)y0, 0), NBOX - 1);
            int xi1 = min(xi0 + 1, NBOX - 1);
            int yi1 = min(yi0 + 1, NBOX - 1);
            int r0 = yi0 - y_lo, r1 = yi1 - y_lo;
            float m0 = ((unsigned)r0 < BROWS) ? 1.f : 0.f;
            float m1 = ((unsigned)r1 < BROWS) ? 1.f : 0.f;
            float w00 = w * (1.f - fx) * (1.f - fy) * m0;
            float w10 = w * fx * (1.f - fy) * m0;
            float w01 = w * (1.f - fx) * fy * m1;
            float w11 = w * fx * fy * m1;
            int a0 = (r0 & (BROWS - 1)) * NBOX;
            int a1 = (r1 & (BROWS - 1)) * NBOX;
            lds_fadd(&tile[a0 + xi0], w00);
            lds_fadd(&tile[a0 + xi1], w10);
            lds_fadd(&tile[a1 + xi0], w01);
            lds_fadd(&tile[a1 + xi1], w11);
        }
    }
    // drain the asm DS atomics (invisible to the compiler's waitcnt pass)
    asm volatile("s_waitcnt lgkmcnt(0)" ::: "memory");
    __syncthreads();
    float* ib = img + (size_t)b * NBOX * NBOX + (size_t)y_lo * NBOX;
    for (int i = tid; i < BROWS * NBOX; i += 1024)
        unsafeAtomicAdd(ib + i, tile[i]);
}

// ---------------- fallback: original fused splat (global atomics) ----------------
__global__ __launch_bounds__(256) void splat_kernel(
    const float* __restrict__ z_x, const float* __restrict__ z_y,
    const float* __restrict__ z_z, const float* __restrict__ Zb,
    const float* __restrict__ coords, const float* __restrict__ weights,
    const float* __restrict__ R, const float* __restrict__ shifts,
    float* __restrict__ img)
{
    __shared__ float s_z[3][NIMG][NL];
    __shared__ float s_R[NIMG][9];
    __shared__ float s_sh[NIMG][2];

    int tid = threadIdx.x;
    for (int i = tid; i < NIMG * NL; i += 256) {
        (&s_z[0][0][0])[i] = z_x[i];
        (&s_z[1][0][0])[i] = z_y[i];
        (&s_z[2][0][0])[i] = z_z[i];
    }
    for (int i = tid; i < NIMG * 9; i += 256) (&s_R[0][0])[i] = R[i];
    if (tid < NIMG * 2) (&s_sh[0][0])[tid] = shifts[tid];
    __syncthreads();

    int p = blockIdx.x * 256 + tid;
    if (p >= NPTS) return;

    float4 zr[16];
    const float4* Zr4 = (const float4*)(Zb + (size_t)p * NL);
    #pragma unroll
    for (int i = 0; i < 16; ++i) zr[i] = Zr4[i];

    float cx0 = coords[3 * p + 0];
    float cy0 = coords[3 * p + 1];
    float cz0 = coords[3 * p + 2];
    float w   = weights[p];

    for (int b = 0; b < NIMG; ++b) {
        const float4* zx4 = (const float4*)s_z[0][b];
        const float4* zy4 = (const float4*)s_z[1][b];
        const float4* zz4 = (const float4*)s_z[2][b];
        float dx = 0.f, dy = 0.f, dz = 0.f;
        #pragma unroll
        for (int i = 0; i < 16; ++i) {
            float4 a = zx4[i];
            dx += a.x * zr[i].x + a.y * zr[i].y + a.z * zr[i].z + a.w * zr[i].w;
            float4 bb = zy4[i];
            dy += bb.x * zr[i].x + bb.y * zr[i].y + bb.z * zr[i].z + bb.w * zr[i].w;
            float4 c = zz4[i];
            dz += c.x * zr[i].x + c.y * zr[i].y + c.z * zr[i].z + c.w * zr[i].w;
        }
        float cx = cx0 + dx, cy = cy0 + dy, cz = cz0 + dz;
        const float* Rb = s_R[b];
        float px = Rb[0] * cx + Rb[1] * cy + Rb[2] * cz + s_sh[b][0] + 128.0f;
        float py = Rb[3] * cx + Rb[4] * cy + Rb[5] * cz + s_sh[b][1] + 128.0f;

        float x0 = floorf(px), y0 = floorf(py);
        float fx = px - x0, fy = py - y0;
        int xi0 = min(max((int)x0, 0), NBOX - 1);
        int yi0 = min(max((int)y0, 0), NBOX - 1);
        int xi1 = min(xi0 + 1, NBOX - 1);
        int yi1 = min(yi0 + 1, NBOX - 1);

        float* ib = img + (size_t)b * NBOX * NBOX;
        unsafeAtomicAdd(ib + yi0 * NBOX + xi0, w * (1.f - fx) * (1.f - fy));
        unsafeAtomicAdd(ib + yi0 * NBOX + xi1, w * fx * (1.f - fy));
        unsafeAtomicAdd(ib + yi1 * NBOX + xi0, w * (1.f - fx) * fy);
        unsafeAtomicAdd(ib + yi1 * NBOX + xi1, w * fx * fy);
    }
}

// ---------------- 5x5 Gaussian blur (zero-padded SAME) ----------------
__global__ __launch_bounds__(256) void blur_kernel(const float* __restrict__ in,
                                                   float* __restrict__ out)
{
    int idx = blockIdx.x * 256 + threadIdx.x;
    int x = idx & (NBOX - 1);
    int y = (idx >> 8) & (NBOX - 1);
    int b = idx >> 16;
    const float* ib = in + (size_t)b * NBOX * NBOX;
    const float gw[5] = {0.0544886845f, 0.2442013420f, 0.4026199469f,
                         0.2442013420f, 0.0544886845f};
    float acc = 0.f;
    #pragma unroll
    for (int dy = -2; dy <= 2; ++dy) {
        int yy = y + dy;
        if (yy < 0 || yy > NBOX - 1) continue;
        float rs = 0.f;
        #pragma unroll
        for (int dx = -2; dx <= 2; ++dx) {
            int xx = x + dx;
            if (xx < 0 || xx > NBOX - 1) continue;
            rs += ib[yy * NBOX + xx] * gw[dx + 2];
        }
        acc += rs * gw[dy + 2];
    }
    out[idx] = acc;
}

// ---------------- 256-pt FFT with LDS twiddle table ----------------
__device__ __forceinline__ void fft_dif_t(float2* s, const float2* tw, int t) {
    #pragma unroll
    for (int st = 7; st >= 0; --st) {
        int half = 1 << st;
        int j  = t & (half - 1);
        int i1 = ((t >> st) << (st + 1)) + j;
        int i2 = i1 + half;
        float2 a = s[i1], b = s[i2];
        float2 w = tw[j << (7 - st)];
        float dxr = a.x - b.x, dxi = a.y - b.y;
        s[i1] = make_float2(a.x + b.x, a.y + b.y);
        s[i2] = make_float2(w.x * dxr - w.y * dxi, w.x * dxi + w.y * dxr);
        __syncthreads();
    }
}

__device__ __forceinline__ void fft_dit_t(float2* s, const float2* tw, int t) {
    #pragma unroll
    for (int st = 0; st < 8; ++st) {
        int half = 1 << st;
        int j  = t & (half - 1);
        int i1 = ((t >> st) << (st + 1)) + j;
        int i2 = i1 + half;
        float2 a = s[i1], b = s[i2];
        float2 w = tw[j << (7 - st)];
        float cs = w.x, sn = -w.y;
        float tr = cs * b.x - sn * b.y;
        float ti = cs * b.y + sn * b.x;
        s[i1] = make_float2(a.x + tr, a.y + ti);
        s[i2] = make_float2(a.x - tr, a.y - ti);
        __syncthreads();
    }
}

__device__ __forceinline__ void init_tw(float2* tw, int tid) {
    if (tid < 128) {
        float sn, cs;
        sincosf(-6.283185307179586f * (float)tid * (1.0f / 256.0f), &sn, &cs);
        tw[tid] = make_float2(cs, sn);
    }
}

__global__ __launch_bounds__(256) void fft_rows_fwd_kernel(const float* __restrict__ in,
                                                           float2* __restrict__ freq)
{
    __shared__ float2 s[2][NBOX];
    __shared__ float2 tw[128];
    int tid = threadIdx.x;
    int tx = tid & 127, ty = tid >> 7;
    init_tw(tw, tid);
    int row = blockIdx.x * 2 + ty;
    const float* rp = in + (size_t)row * NBOX;
    s[ty][tx]       = make_float2(rp[tx], 0.f);
    s[ty][tx + 128] = make_float2(rp[tx + 128], 0.f);
    __syncthreads();
    fft_dif_t(s[ty], tw, tx);
    float2* op = freq + (size_t)row * NBOX;
    op[tx]       = s[ty][tx];
    op[tx + 128] = s[ty][tx + 128];
}

__global__ __launch_bounds__(256) void fft_cols_ctf_kernel(float2* __restrict__ freq,
                                                           const float* __restrict__ ctf)
{
    __shared__ float2 s[2][NBOX];
    __shared__ float2 tw[128];
    int tid = threadIdx.x;
    int tx = tid & 127, ty = tid >> 7;
    init_tw(tw, tid);
    int gid = blockIdx.x * 2 + ty;
    int b = gid >> 8, x = gid & (NBOX - 1);
    float2* col = freq + (size_t)b * NBOX * NBOX + x;
    s[ty][tx]       = col[tx * NBOX];
    s[ty][tx + 128] = col[(tx + 128) * NBOX];
    __syncthreads();
    fft_dif_t(s[ty], tw, tx);
    const float* cb = ctf + (size_t)b * NBOX * NBOX + rev8(x);
    float c0 = cb[rev8(tx) * NBOX];
    float c1 = cb[rev8(tx + 128) * NBOX];
    s[ty][tx].x       *= c0;  s[ty][tx].y       *= c0;
    s[ty][tx + 128].x *= c1;  s[ty][tx + 128].y *= c1;
    __syncthreads();
    fft_dit_t(s[ty], tw, tx);
    const float inv = 1.0f / 256.0f;
    col[tx * NBOX]         = make_float2(s[ty][tx].x * inv,       s[ty][tx].y * inv);
    col[(tx + 128) * NBOX] = make_float2(s[ty][tx + 128].x * inv, s[ty][tx + 128].y * inv);
}

__global__ __launch_bounds__(256) void fft_rows_inv_kernel(const float2* __restrict__ freq,
                                                           float* __restrict__ out)
{
    __shared__ float2 s[2][NBOX];
    __shared__ float2 tw[128];
    int tid = threadIdx.x;
    int tx = tid & 127, ty = tid >> 7;
    init_tw(tw, tid);
    int row = blockIdx.x * 2 + ty;
    const float2* rp = freq + (size_t)row * NBOX;
    s[ty][tx]       = rp[tx];
    s[ty][tx + 128] = rp[tx + 128];
    __syncthreads();
    fft_dit_t(s[ty], tw, tx);
    const float inv = 1.0f / 256.0f;
    out[(size_t)row * NBOX + tx]       = s[ty][tx].x * inv;
    out[(size_t)row * NBOX + tx + 128] = s[ty][tx + 128].x * inv;
}

extern "C" void kernel_launch(void* const* d_in, const int* in_sizes, int n_in,
                              void* d_out, int out_size, void* d_ws, size_t ws_size,
                              hipStream_t stream)
{
    (void)in_sizes; (void)n_in; (void)out_size;
    const float* z_x     = (const float*)d_in[0];
    const float* z_y     = (const float*)d_in[1];
    const float* z_z     = (const float*)d_in[2];
    const float* Zb      = (const float*)d_in[3];
    const float* coords  = (const float*)d_in[4];
    const float* weights = (const float*)d_in[5];
    const float* R       = (const float*)d_in[6];
    const float* shifts  = (const float*)d_in[7];
    const float* ctf     = (const float*)d_in[8];
    float* out = (float*)d_out;

    const size_t NELEM = (size_t)NIMG * NBOX * NBOX;           // 2,097,152
    const size_t NPAIR = (size_t)NIMG * NPTS;                  // 9.6 M
    float*  img  = (float*)d_ws;
    float*  blur = img + NELEM;
    float2* freq = (float2*)(blur + NELEM);
    float2* pairs = (float2*)(freq + NELEM);
    const size_t required = (4 * NELEM + 2 * NPAIR) * sizeof(float);

    zero_kernel<<<(int)(NELEM / 4 + 255) / 256, 256, 0, stream>>>((float4*)img, (int)(NELEM / 4));

    if (ws_size >= required) {
        project_kernel<<<(NPTS + 255) / 256, 256, 0, stream>>>(z_x, z_y, z_z, Zb, coords,
                                                               R, shifts, pairs);
        splat2_kernel<<<NIMG * BANDS * CHUNKS, 1024, 0, stream>>>(pairs, weights, img);
    } else {
        splat_kernel<<<(NPTS + 255) / 256, 256, 0, stream>>>(z_x, z_y, z_z, Zb, coords,
                                                             weights, R, shifts, img);
    }

    blur_kernel<<<(int)(NELEM / 256), 256, 0, stream>>>(img, blur);
    fft_rows_fwd_kernel<<<NIMG * NBOX / 2, 256, 0, stream>>>(blur, freq);
    fft_cols_ctf_kernel<<<NIMG * NBOX / 2, 256, 0, stream>>>(freq, ctf);
    fft_rows_inv_kernel<<<NIMG * NBOX / 2, 256, 0, stream>>>(freq, out);
}

// Round 8
// 390.294 us; speedup vs baseline: 1.6908x; 1.6908x over previous
//
#include <hip/hip_runtime.h>
#include <hip/hip_bf16.h>

#define NIMG 32
#define NPTS 300000
#define NL   64
#define NBOX 256

#define BANDS  8
#define BROWS  32          // NBOX / BANDS
#define CHUNKS 2
#define CHPTS  (NPTS / CHUNKS)   // 150000
#define NGROUP (NIMG * CHUNKS)   // 64

typedef float v2f __attribute__((ext_vector_type(2)));

__device__ __forceinline__ int rev8(int x) { return (int)(__brev((unsigned)x) >> 24); }

// native LDS float atomic add (ds_add_f32, no return).
__device__ __forceinline__ void lds_fadd(float* p, float v) {
    unsigned off = (unsigned)(uintptr_t)p;
    asm volatile("ds_add_f32 %0, %1" :: "v"(off), "v"(v));
}

// ---------------- zero fill ----------------
__global__ __launch_bounds__(256) void zero_kernel(float4* p, int n4) {
    int i = blockIdx.x * 256 + threadIdx.x;
    if (i < n4) p[i] = make_float4(0.f, 0.f, 0.f, 0.f);
}

// ---------------- Pass 1: deformation + rotate + shift -> interleaved (px,py) ----------------
__global__ __launch_bounds__(256) void project_kernel(
    const float* __restrict__ z_x, const float* __restrict__ z_y,
    const float* __restrict__ z_z, const float* __restrict__ Zb,
    const float* __restrict__ coords,
    const float* __restrict__ R, const float* __restrict__ shifts,
    float2* __restrict__ pairs)
{
    __shared__ float s_z[3][NIMG][NL];   // 24 KB
    __shared__ float s_R[NIMG][9];
    __shared__ float s_sh[NIMG][2];

    int tid = threadIdx.x;
    for (int i = tid; i < NIMG * NL; i += 256) {
        (&s_z[0][0][0])[i] = z_x[i];
        (&s_z[1][0][0])[i] = z_y[i];
        (&s_z[2][0][0])[i] = z_z[i];
    }
    for (int i = tid; i < NIMG * 9; i += 256) (&s_R[0][0])[i] = R[i];
    if (tid < NIMG * 2) (&s_sh[0][0])[tid] = shifts[tid];
    __syncthreads();

    int p = blockIdx.x * 256 + tid;
    if (p >= NPTS) return;

    // Z row into registers as 32 v2f pairs (ds/global b64-friendly, pk-fma shape)
    v2f zr[32];
    {
        const float4* Zr4 = (const float4*)(Zb + (size_t)p * NL);
        float4 tmp[16];
        #pragma unroll
        for (int i = 0; i < 16; ++i) tmp[i] = Zr4[i];
        const v2f* t2 = (const v2f*)tmp;
        #pragma unroll
        for (int i = 0; i < 32; ++i) zr[i] = t2[i];
    }

    float cx0 = coords[3 * p + 0];
    float cy0 = coords[3 * p + 1];
    float cz0 = coords[3 * p + 2];

    for (int b = 0; b < NIMG; ++b) {
        const v2f* zx2 = (const v2f*)s_z[0][b];
        const v2f* zy2 = (const v2f*)s_z[1][b];
        const v2f* zz2 = (const v2f*)s_z[2][b];
        v2f ax = {0.f, 0.f}, ay = {0.f, 0.f}, az = {0.f, 0.f};
        #pragma unroll
        for (int i = 0; i < 32; ++i) {
            ax += zx2[i] * zr[i];
            ay += zy2[i] * zr[i];
            az += zz2[i] * zr[i];
        }
        float cx = cx0 + ax.x + ax.y;
        float cy = cy0 + ay.x + ay.y;
        float cz = cz0 + az.x + az.y;
        const float* Rb = s_R[b];
        float px = Rb[0] * cx + Rb[1] * cy + Rb[2] * cz + s_sh[b][0] + 128.0f;
        float py = Rb[3] * cx + Rb[4] * cy + Rb[5] * cz + s_sh[b][1] + 128.0f;
        pairs[(size_t)b * NPTS + p] = make_float2(px, py);
    }
}

// ---------------- Pass 2: LDS-privatized band splat (R6 structure, unchanged) ----------------
__global__ __launch_bounds__(256) void splat2_kernel(
    const float2* __restrict__ pairs, const float* __restrict__ weights,
    float* __restrict__ img)
{
    __shared__ float tile[BROWS * NBOX];   // 32 KB
    int tid = threadIdx.x;
    int id = blockIdx.x;
    int band = id >> 6;           // 0..7
    int g    = id & 63;           // group = b*CHUNKS + c
    int b = g >> 1, c = g & 1;

    float4* t4 = (float4*)tile;
    for (int i = tid; i < BROWS * NBOX / 4; i += 256)
        t4[i] = make_float4(0.f, 0.f, 0.f, 0.f);
    __syncthreads();

    const int y_lo = band * BROWS;
    const float2* pp = pairs + (size_t)b * NPTS + (size_t)c * CHPTS;
    const float*  wp = weights + (size_t)c * CHPTS;

    for (int i = 4 * tid; i < CHPTS; i += 1024) {
        float4 q0 = *(const float4*)(pp + i);       // points i, i+1
        float4 q1 = *(const float4*)(pp + i + 2);   // points i+2, i+3
        float4 wv = *(const float4*)(wp + i);
        float pxa[4] = {q0.x, q0.z, q1.x, q1.z};
        float pya[4] = {q0.y, q0.w, q1.y, q1.w};
        float wa[4]  = {wv.x, wv.y, wv.z, wv.w};
        #pragma unroll
        for (int k = 0; k < 4; ++k) {
            float px = pxa[k], py = pya[k], w = wa[k];
            float x0 = floorf(px), y0 = floorf(py);
            float fx = px - x0, fy = py - y0;
            int xi0 = min(max((int)x0, 0), NBOX - 1);
            int yi0 = min(max((int)y0, 0), NBOX - 1);
            int xi1 = min(xi0 + 1, NBOX - 1);
            int yi1 = min(yi0 + 1, NBOX - 1);
            float w00 = w * (1.f - fx) * (1.f - fy);
            float w10 = w * fx * (1.f - fy);
            float w01 = w * (1.f - fx) * fy;
            float w11 = w * fx * fy;
            int r0 = yi0 - y_lo, r1 = yi1 - y_lo;
            if ((unsigned)r0 < BROWS) {
                lds_fadd(&tile[r0 * NBOX + xi0], w00);
                lds_fadd(&tile[r0 * NBOX + xi1], w10);
            }
            if ((unsigned)r1 < BROWS) {
                lds_fadd(&tile[r1 * NBOX + xi0], w01);
                lds_fadd(&tile[r1 * NBOX + xi1], w11);
            }
        }
    }
    // drain the asm DS atomics (invisible to the compiler's waitcnt pass)
    asm volatile("s_waitcnt lgkmcnt(0)" ::: "memory");
    __syncthreads();
    float* ib = img + (size_t)b * NBOX * NBOX + (size_t)y_lo * NBOX;
    for (int i = tid; i < BROWS * NBOX; i += 256)
        unsafeAtomicAdd(ib + i, tile[i]);
}

// ---------------- fallback: fused splat with global atomics (small ws) ----------------
__global__ __launch_bounds__(256) void splat_kernel(
    const float* __restrict__ z_x, const float* __restrict__ z_y,
    const float* __restrict__ z_z, const float* __restrict__ Zb,
    const float* __restrict__ coords, const float* __restrict__ weights,
    const float* __restrict__ R, const float* __restrict__ shifts,
    float* __restrict__ img)
{
    __shared__ float s_z[3][NIMG][NL];
    __shared__ float s_R[NIMG][9];
    __shared__ float s_sh[NIMG][2];

    int tid = threadIdx.x;
    for (int i = tid; i < NIMG * NL; i += 256) {
        (&s_z[0][0][0])[i] = z_x[i];
        (&s_z[1][0][0])[i] = z_y[i];
        (&s_z[2][0][0])[i] = z_z[i];
    }
    for (int i = tid; i < NIMG * 9; i += 256) (&s_R[0][0])[i] = R[i];
    if (tid < NIMG * 2) (&s_sh[0][0])[tid] = shifts[tid];
    __syncthreads();

    int p = blockIdx.x * 256 + tid;
    if (p >= NPTS) return;

    float4 zr[16];
    const float4* Zr4 = (const float4*)(Zb + (size_t)p * NL);
    #pragma unroll
    for (int i = 0; i < 16; ++i) zr[i] = Zr4[i];

    float cx0 = coords[3 * p + 0];
    float cy0 = coords[3 * p + 1];
    float cz0 = coords[3 * p + 2];
    float w   = weights[p];

    for (int b = 0; b < NIMG; ++b) {
        const float4* zx4 = (const float4*)s_z[0][b];
        const float4* zy4 = (const float4*)s_z[1][b];
        const float4* zz4 = (const float4*)s_z[2][b];
        float dx = 0.f, dy = 0.f, dz = 0.f;
        #pragma unroll
        for (int i = 0; i < 16; ++i) {
            float4 a = zx4[i];
            dx += a.x * zr[i].x + a.y * zr[i].y + a.z * zr[i].z + a.w * zr[i].w;
            float4 bb = zy4[i];
            dy += bb.x * zr[i].x + bb.y * zr[i].y + bb.z * zr[i].z + bb.w * zr[i].w;
            float4 c = zz4[i];
            dz += c.x * zr[i].x + c.y * zr[i].y + c.z * zr[i].z + c.w * zr[i].w;
        }
        float cx = cx0 + dx, cy = cy0 + dy, cz = cz0 + dz;
        const float* Rb = s_R[b];
        float px = Rb[0] * cx + Rb[1] * cy + Rb[2] * cz + s_sh[b][0] + 128.0f;
        float py = Rb[3] * cx + Rb[4] * cy + Rb[5] * cz + s_sh[b][1] + 128.0f;

        float x0 = floorf(px), y0 = floorf(py);
        float fx = px - x0, fy = py - y0;
        int xi0 = min(max((int)x0, 0), NBOX - 1);
        int yi0 = min(max((int)y0, 0), NBOX - 1);
        int xi1 = min(xi0 + 1, NBOX - 1);
        int yi1 = min(yi0 + 1, NBOX - 1);

        float* ib = img + (size_t)b * NBOX * NBOX;
        unsafeAtomicAdd(ib + yi0 * NBOX + xi0, w * (1.f - fx) * (1.f - fy));
        unsafeAtomicAdd(ib + yi0 * NBOX + xi1, w * fx * (1.f - fy));
        unsafeAtomicAdd(ib + yi1 * NBOX + xi0, w * (1.f - fx) * fy);
        unsafeAtomicAdd(ib + yi1 * NBOX + xi1, w * fx * fy);
    }
}

// ---------------- 256-pt FFT helpers (AOS float2, LDS twiddle) ----------------
__device__ __forceinline__ void fft_dif_t(float2* s, const float2* tw, int t) {
    #pragma unroll
    for (int st = 7; st >= 0; --st) {
        int half = 1 << st;
        int j  = t & (half - 1);
        int i1 = ((t >> st) << (st + 1)) + j;
        int i2 = i1 + half;
        float2 a = s[i1], b = s[i2];
        float2 w = tw[j << (7 - st)];
        float dxr = a.x - b.x, dxi = a.y - b.y;
        s[i1] = make_float2(a.x + b.x, a.y + b.y);
        s[i2] = make_float2(w.x * dxr - w.y * dxi, w.x * dxi + w.y * dxr);
        __syncthreads();
    }
}

__device__ __forceinline__ void fft_dit_t(float2* s, const float2* tw, int t) {
    #pragma unroll
    for (int st = 0; st < 8; ++st) {
        int half = 1 << st;
        int j  = t & (half - 1);
        int i1 = ((t >> st) << (st + 1)) + j;
        int i2 = i1 + half;
        float2 a = s[i1], b = s[i2];
        float2 w = tw[j << (7 - st)];
        float cs = w.x, sn = -w.y;
        float tr = cs * b.x - sn * b.y;
        float ti = cs * b.y + sn * b.x;
        s[i1] = make_float2(a.x + tr, a.y + ti);
        s[i2] = make_float2(a.x - tr, a.y - ti);
        __syncthreads();
    }
}

// ---------------- SOA FFT helpers (for 8-col kernel) ----------------
__device__ __forceinline__ void fft_dif_soa(float* re, float* im, const float2* tw, int t) {
    #pragma unroll
    for (int st = 7; st >= 0; --st) {
        int half = 1 << st;
        int j  = t & (half - 1);
        int i1 = ((t >> st) << (st + 1)) + j;
        int i2 = i1 + half;
        float ar = re[i1], ai = im[i1], br = re[i2], bi = im[i2];
        float2 w = tw[j << (7 - st)];
        float dr = ar - br, di = ai - bi;
        re[i1] = ar + br;  im[i1] = ai + bi;
        re[i2] = w.x * dr - w.y * di;
        im[i2] = w.x * di + w.y * dr;
        __syncthreads();
    }
}

__device__ __forceinline__ void fft_dit_soa(float* re, float* im, const float2* tw, int t) {
    #pragma unroll
    for (int st = 0; st < 8; ++st) {
        int half = 1 << st;
        int j  = t & (half - 1);
        int i1 = ((t >> st) << (st + 1)) + j;
        int i2 = i1 + half;
        float ar = re[i1], ai = im[i1], br = re[i2], bi = im[i2];
        float2 w = tw[j << (7 - st)];
        float cs = w.x, sn = -w.y;
        float tr = cs * br - sn * bi;
        float ti = cs * bi + sn * br;
        re[i1] = ar + tr;  im[i1] = ai + ti;
        re[i2] = ar - tr;  im[i2] = ai - ti;
        __syncthreads();
    }
}

__device__ __forceinline__ void init_tw(float2* tw, int tid) {
    if (tid < 128) {
        float sn, cs;
        sincosf(-6.283185307179586f * (float)tid * (1.0f / 256.0f), &sn, &cs);
        tw[tid] = make_float2(cs, sn);
    }
}

// ---------------- Pass A: fused 5x5 blur + forward row FFT ----------------
__global__ __launch_bounds__(256) void fft_rows_fwd_blur_kernel(const float* __restrict__ img,
                                                                float2* __restrict__ freq)
{
    __shared__ float2 s[2][NBOX];
    __shared__ float  sb[2][NBOX];
    __shared__ float2 tw[128];
    int tid = threadIdx.x;
    int tx = tid & 127, ty = tid >> 7;
    init_tw(tw, tid);
    int row = blockIdx.x * 2 + ty;     // 0 .. B*N-1
    int b = row >> 8, y = row & (NBOX - 1);
    const float* ib = img + ((size_t)b << 16);
    const float gw[5] = {0.0544886845f, 0.2442013420f, 0.4026199469f,
                         0.2442013420f, 0.0544886845f};
    // vertical 5-tap (zero-padded)
    float acc0 = 0.f, acc1 = 0.f;
    #pragma unroll
    for (int dy = -2; dy <= 2; ++dy) {
        int yy = y + dy;
        if ((unsigned)yy < (unsigned)NBOX) {
            const float* rp = ib + yy * NBOX;
            acc0 += gw[dy + 2] * rp[tx];
            acc1 += gw[dy + 2] * rp[tx + 128];
        }
    }
    sb[ty][tx] = acc0;  sb[ty][tx + 128] = acc1;
    __syncthreads();
    // horizontal 5-tap (zero-padded)
    float r0 = 0.f, r1 = 0.f;
    #pragma unroll
    for (int dx = -2; dx <= 2; ++dx) {
        int x0 = tx + dx, x1 = tx + 128 + dx;
        if ((unsigned)x0 < (unsigned)NBOX) r0 += gw[dx + 2] * sb[ty][x0];
        if ((unsigned)x1 < (unsigned)NBOX) r1 += gw[dx + 2] * sb[ty][x1];
    }
    s[ty][tx]       = make_float2(r0, 0.f);
    s[ty][tx + 128] = make_float2(r1, 0.f);
    __syncthreads();
    fft_dif_t(s[ty], tw, tx);
    float2* op = freq + (size_t)row * NBOX;
    op[tx]       = s[ty][tx];
    op[tx + 128] = s[ty][tx + 128];
}

// ---------------- Pass B: 8-column fused fwd-FFT * ctf * inv-FFT ----------------
__global__ __launch_bounds__(1024) void fft_cols_ctf8_kernel(float2* __restrict__ freq,
                                                             const float* __restrict__ ctf)
{
    __shared__ float  s_re[8][257];
    __shared__ float  s_im[8][257];
    __shared__ float2 tw[128];
    int tid = threadIdx.x;
    init_tw(tw, tid);
    int col = tid & 7, j = tid >> 3;          // j in 0..127
    int blk = blockIdx.x;
    int b = blk >> 5;
    int x = ((blk & 31) << 3) + col;          // storage x
    float2* base = freq + ((size_t)b << 16) + x;

    float2 v0 = base[(size_t)j * NBOX];
    float2 v1 = base[(size_t)(j + 128) * NBOX];
    s_re[col][j] = v0.x;        s_im[col][j] = v0.y;
    s_re[col][j + 128] = v1.x;  s_im[col][j + 128] = v1.y;
    __syncthreads();

    fft_dif_soa(s_re[col], s_im[col], tw, j);

    // storage index i holds y-freq rev8(i); this column holds x-freq rev8(x)
    const float* cb = ctf + ((size_t)b << 16) + rev8(x);
    float c0 = cb[rev8(j) * NBOX];
    float c1 = cb[rev8(j + 128) * NBOX];
    s_re[col][j] *= c0;        s_im[col][j] *= c0;
    s_re[col][j + 128] *= c1;  s_im[col][j + 128] *= c1;
    __syncthreads();

    fft_dit_soa(s_re[col], s_im[col], tw, j);

    const float inv = 1.0f / 256.0f;
    base[(size_t)j * NBOX]         = make_float2(s_re[col][j] * inv, s_im[col][j] * inv);
    base[(size_t)(j + 128) * NBOX] = make_float2(s_re[col][j + 128] * inv, s_im[col][j + 128] * inv);
}

// ---------------- Pass C: inverse row FFT -> real output ----------------
__global__ __launch_bounds__(256) void fft_rows_inv_kernel(const float2* __restrict__ freq,
                                                           float* __restrict__ out)
{
    __shared__ float2 s[2][NBOX];
    __shared__ float2 tw[128];
    int tid = threadIdx.x;
    int tx = tid & 127, ty = tid >> 7;
    init_tw(tw, tid);
    int row = blockIdx.x * 2 + ty;
    const float2* rp = freq + (size_t)row * NBOX;
    s[ty][tx]       = rp[tx];
    s[ty][tx + 128] = rp[tx + 128];
    __syncthreads();
    fft_dit_t(s[ty], tw, tx);
    const float inv = 1.0f / 256.0f;
    out[(size_t)row * NBOX + tx]       = s[ty][tx].x * inv;
    out[(size_t)row * NBOX + tx + 128] = s[ty][tx + 128].x * inv;
}

extern "C" void kernel_launch(void* const* d_in, const int* in_sizes, int n_in,
                              void* d_out, int out_size, void* d_ws, size_t ws_size,
                              hipStream_t stream)
{
    (void)in_sizes; (void)n_in; (void)out_size;
    const float* z_x     = (const float*)d_in[0];
    const float* z_y     = (const float*)d_in[1];
    const float* z_z     = (const float*)d_in[2];
    const float* Zb      = (const float*)d_in[3];
    const float* coords  = (const float*)d_in[4];
    const float* weights = (const float*)d_in[5];
    const float* R       = (const float*)d_in[6];
    const float* shifts  = (const float*)d_in[7];
    const float* ctf     = (const float*)d_in[8];
    float* out = (float*)d_out;

    const size_t NELEM = (size_t)NIMG * NBOX * NBOX;           // 2,097,152
    const size_t NPAIR = (size_t)NIMG * NPTS;                  // 9.6 M
    float*  img   = (float*)d_ws;                              // 8 MB
    float2* freq  = (float2*)(img + NELEM);                    // 16 MB
    float2* pairs = freq + NELEM;                              // 76.8 MB
    const size_t required = NELEM * 4 + NELEM * 8 + NPAIR * 8;

    zero_kernel<<<(int)(NELEM / 4 + 255) / 256, 256, 0, stream>>>((float4*)img, (int)(NELEM / 4));

    if (ws_size >= required) {
        project_kernel<<<(NPTS + 255) / 256, 256, 0, stream>>>(z_x, z_y, z_z, Zb, coords,
                                                               R, shifts, pairs);
        splat2_kernel<<<NGROUP * BANDS, 256, 0, stream>>>(pairs, weights, img);
    } else {
        splat_kernel<<<(NPTS + 255) / 256, 256, 0, stream>>>(z_x, z_y, z_z, Zb, coords,
                                                             weights, R, shifts, img);
    }

    // fused blur + row FFT
    fft_rows_fwd_blur_kernel<<<NIMG * NBOX / 2, 256, 0, stream>>>(img, freq);
    // 8-column fused col-FFT * ctf * inv-col-FFT
    fft_cols_ctf8_kernel<<<NIMG * 32, 1024, 0, stream>>>(freq, ctf);
    // inverse row FFT -> real out
    fft_rows_inv_kernel<<<NIMG * NBOX / 2, 256, 0, stream>>>(freq, out);
}

// Round 9
// 389.623 us; speedup vs baseline: 1.6937x; 1.0017x over previous
//
#include <hip/hip_runtime.h>
#include <hip/hip_bf16.h>

#define NIMG 32
#define NPTS 300000
#define NL   64
#define NBOX 256

#define BANDS  8
#define BROWS  32          // NBOX / BANDS
#define CHUNKS 2
#define CHPTS  (NPTS / CHUNKS)   // 150000
#define NGROUP (NIMG * CHUNKS)   // 64

typedef float v2f __attribute__((ext_vector_type(2)));

__device__ __forceinline__ int rev8(int x) { return (int)(__brev((unsigned)x) >> 24); }

// LDS float atomic add via compiler intrinsic: lowers to ds_add_f32 (no rtn),
// fully visible to the waitcnt pass -> no conservative per-op lgkmcnt(0) drain
// (that drain was the R4-R8 splat wall: inline-asm ds_add forced ~200cy
// serialization per atomic).
__device__ __forceinline__ void lds_fadd(float* p, float v) {
    (void)__hip_atomic_fetch_add(p, v, __ATOMIC_RELAXED, __HIP_MEMORY_SCOPE_WORKGROUP);
}

// ---------------- zero fill ----------------
__global__ __launch_bounds__(256) void zero_kernel(float4* p, int n4) {
    int i = blockIdx.x * 256 + threadIdx.x;
    if (i < n4) p[i] = make_float4(0.f, 0.f, 0.f, 0.f);
}

// ---------------- Pass 1: deformation + rotate + shift -> interleaved (px,py) ----------------
__global__ __launch_bounds__(256) void project_kernel(
    const float* __restrict__ z_x, const float* __restrict__ z_y,
    const float* __restrict__ z_z, const float* __restrict__ Zb,
    const float* __restrict__ coords,
    const float* __restrict__ R, const float* __restrict__ shifts,
    float2* __restrict__ pairs)
{
    __shared__ float s_z[3][NIMG][NL];   // 24 KB
    __shared__ float s_R[NIMG][9];
    __shared__ float s_sh[NIMG][2];

    int tid = threadIdx.x;
    for (int i = tid; i < NIMG * NL; i += 256) {
        (&s_z[0][0][0])[i] = z_x[i];
        (&s_z[1][0][0])[i] = z_y[i];
        (&s_z[2][0][0])[i] = z_z[i];
    }
    for (int i = tid; i < NIMG * 9; i += 256) (&s_R[0][0])[i] = R[i];
    if (tid < NIMG * 2) (&s_sh[0][0])[tid] = shifts[tid];
    __syncthreads();

    int p = blockIdx.x * 256 + tid;
    if (p >= NPTS) return;

    // Z row into registers as 32 v2f pairs
    v2f zr[32];
    {
        const float4* Zr4 = (const float4*)(Zb + (size_t)p * NL);
        float4 tmp[16];
        #pragma unroll
        for (int i = 0; i < 16; ++i) tmp[i] = Zr4[i];
        const v2f* t2 = (const v2f*)tmp;
        #pragma unroll
        for (int i = 0; i < 32; ++i) zr[i] = t2[i];
    }

    float cx0 = coords[3 * p + 0];
    float cy0 = coords[3 * p + 1];
    float cz0 = coords[3 * p + 2];

    for (int b = 0; b < NIMG; ++b) {
        const v2f* zx2 = (const v2f*)s_z[0][b];
        const v2f* zy2 = (const v2f*)s_z[1][b];
        const v2f* zz2 = (const v2f*)s_z[2][b];
        v2f ax = {0.f, 0.f}, ay = {0.f, 0.f}, az = {0.f, 0.f};
        #pragma unroll
        for (int i = 0; i < 32; ++i) {
            ax += zx2[i] * zr[i];
            ay += zy2[i] * zr[i];
            az += zz2[i] * zr[i];
        }
        float cx = cx0 + ax.x + ax.y;
        float cy = cy0 + ay.x + ay.y;
        float cz = cz0 + az.x + az.y;
        const float* Rb = s_R[b];
        float px = Rb[0] * cx + Rb[1] * cy + Rb[2] * cz + s_sh[b][0] + 128.0f;
        float py = Rb[3] * cx + Rb[4] * cy + Rb[5] * cz + s_sh[b][1] + 128.0f;
        pairs[(size_t)b * NPTS + p] = make_float2(px, py);
    }
}

// ---------------- Pass 2: LDS-privatized band splat (intrinsic ds_add_f32) ----------------
__global__ __launch_bounds__(256) void splat2_kernel(
    const float2* __restrict__ pairs, const float* __restrict__ weights,
    float* __restrict__ img)
{
    __shared__ float tile[BROWS * NBOX];   // 32 KB
    int tid = threadIdx.x;
    int id = blockIdx.x;
    int band = id >> 6;           // 0..7
    int g    = id & 63;           // group = b*CHUNKS + c
    int b = g >> 1, c = g & 1;

    float4* t4 = (float4*)tile;
    for (int i = tid; i < BROWS * NBOX / 4; i += 256)
        t4[i] = make_float4(0.f, 0.f, 0.f, 0.f);
    __syncthreads();

    const int y_lo = band * BROWS;
    const float2* pp = pairs + (size_t)b * NPTS + (size_t)c * CHPTS;
    const float*  wp = weights + (size_t)c * CHPTS;

    for (int i = 4 * tid; i < CHPTS; i += 1024) {
        float4 q0 = *(const float4*)(pp + i);       // points i, i+1
        float4 q1 = *(const float4*)(pp + i + 2);   // points i+2, i+3
        float4 wv = *(const float4*)(wp + i);
        float pxa[4] = {q0.x, q0.z, q1.x, q1.z};
        float pya[4] = {q0.y, q0.w, q1.y, q1.w};
        float wa[4]  = {wv.x, wv.y, wv.z, wv.w};
        #pragma unroll
        for (int k = 0; k < 4; ++k) {
            float px = pxa[k], py = pya[k], w = wa[k];
            float x0 = floorf(px), y0 = floorf(py);
            float fx = px - x0, fy = py - y0;
            int xi0 = min(max((int)x0, 0), NBOX - 1);
            int yi0 = min(max((int)y0, 0), NBOX - 1);
            int xi1 = min(xi0 + 1, NBOX - 1);
            int yi1 = min(yi0 + 1, NBOX - 1);
            float w00 = w * (1.f - fx) * (1.f - fy);
            float w10 = w * fx * (1.f - fy);
            float w01 = w * (1.f - fx) * fy;
            float w11 = w * fx * fy;
            int r0 = yi0 - y_lo, r1 = yi1 - y_lo;
            if ((unsigned)r0 < BROWS) {
                lds_fadd(&tile[r0 * NBOX + xi0], w00);
                lds_fadd(&tile[r0 * NBOX + xi1], w10);
            }
            if ((unsigned)r1 < BROWS) {
                lds_fadd(&tile[r1 * NBOX + xi0], w01);
                lds_fadd(&tile[r1 * NBOX + xi1], w11);
            }
        }
    }
    __syncthreads();
    float* ib = img + (size_t)b * NBOX * NBOX + (size_t)y_lo * NBOX;
    for (int i = tid; i < BROWS * NBOX; i += 256)
        unsafeAtomicAdd(ib + i, tile[i]);
}

// ---------------- fallback: fused splat with global atomics (small ws) ----------------
__global__ __launch_bounds__(256) void splat_kernel(
    const float* __restrict__ z_x, const float* __restrict__ z_y,
    const float* __restrict__ z_z, const float* __restrict__ Zb,
    const float* __restrict__ coords, const float* __restrict__ weights,
    const float* __restrict__ R, const float* __restrict__ shifts,
    float* __restrict__ img)
{
    __shared__ float s_z[3][NIMG][NL];
    __shared__ float s_R[NIMG][9];
    __shared__ float s_sh[NIMG][2];

    int tid = threadIdx.x;
    for (int i = tid; i < NIMG * NL; i += 256) {
        (&s_z[0][0][0])[i] = z_x[i];
        (&s_z[1][0][0])[i] = z_y[i];
        (&s_z[2][0][0])[i] = z_z[i];
    }
    for (int i = tid; i < NIMG * 9; i += 256) (&s_R[0][0])[i] = R[i];
    if (tid < NIMG * 2) (&s_sh[0][0])[tid] = shifts[tid];
    __syncthreads();

    int p = blockIdx.x * 256 + tid;
    if (p >= NPTS) return;

    float4 zr[16];
    const float4* Zr4 = (const float4*)(Zb + (size_t)p * NL);
    #pragma unroll
    for (int i = 0; i < 16; ++i) zr[i] = Zr4[i];

    float cx0 = coords[3 * p + 0];
    float cy0 = coords[3 * p + 1];
    float cz0 = coords[3 * p + 2];
    float w   = weights[p];

    for (int b = 0; b < NIMG; ++b) {
        const float4* zx4 = (const float4*)s_z[0][b];
        const float4* zy4 = (const float4*)s_z[1][b];
        const float4* zz4 = (const float4*)s_z[2][b];
        float dx = 0.f, dy = 0.f, dz = 0.f;
        #pragma unroll
        for (int i = 0; i < 16; ++i) {
            float4 a = zx4[i];
            dx += a.x * zr[i].x + a.y * zr[i].y + a.z * zr[i].z + a.w * zr[i].w;
            float4 bb = zy4[i];
            dy += bb.x * zr[i].x + bb.y * zr[i].y + bb.z * zr[i].z + bb.w * zr[i].w;
            float4 c = zz4[i];
            dz += c.x * zr[i].x + c.y * zr[i].y + c.z * zr[i].z + c.w * zr[i].w;
        }
        float cx = cx0 + dx, cy = cy0 + dy, cz = cz0 + dz;
        const float* Rb = s_R[b];
        float px = Rb[0] * cx + Rb[1] * cy + Rb[2] * cz + s_sh[b][0] + 128.0f;
        float py = Rb[3] * cx + Rb[4] * cy + Rb[5] * cz + s_sh[b][1] + 128.0f;

        float x0 = floorf(px), y0 = floorf(py);
        float fx = px - x0, fy = py - y0;
        int xi0 = min(max((int)x0, 0), NBOX - 1);
        int yi0 = min(max((int)y0, 0), NBOX - 1);
        int xi1 = min(xi0 + 1, NBOX - 1);
        int yi1 = min(yi0 + 1, NBOX - 1);

        float* ib = img + (size_t)b * NBOX * NBOX;
        unsafeAtomicAdd(ib + yi0 * NBOX + xi0, w * (1.f - fx) * (1.f - fy));
        unsafeAtomicAdd(ib + yi0 * NBOX + xi1, w * fx * (1.f - fy));
        unsafeAtomicAdd(ib + yi1 * NBOX + xi0, w * (1.f - fx) * fy);
        unsafeAtomicAdd(ib + yi1 * NBOX + xi1, w * fx * fy);
    }
}

// ---------------- 256-pt FFT helpers (AOS float2, LDS twiddle) ----------------
__device__ __forceinline__ void fft_dif_t(float2* s, const float2* tw, int t) {
    #pragma unroll
    for (int st = 7; st >= 0; --st) {
        int half = 1 << st;
        int j  = t & (half - 1);
        int i1 = ((t >> st) << (st + 1)) + j;
        int i2 = i1 + half;
        float2 a = s[i1], b = s[i2];
        float2 w = tw[j << (7 - st)];
        float dxr = a.x - b.x, dxi = a.y - b.y;
        s[i1] = make_float2(a.x + b.x, a.y + b.y);
        s[i2] = make_float2(w.x * dxr - w.y * dxi, w.x * dxi + w.y * dxr);
        __syncthreads();
    }
}

__device__ __forceinline__ void fft_dit_t(float2* s, const float2* tw, int t) {
    #pragma unroll
    for (int st = 0; st < 8; ++st) {
        int half = 1 << st;
        int j  = t & (half - 1);
        int i1 = ((t >> st) << (st + 1)) + j;
        int i2 = i1 + half;
        float2 a = s[i1], b = s[i2];
        float2 w = tw[j << (7 - st)];
        float cs = w.x, sn = -w.y;
        float tr = cs * b.x - sn * b.y;
        float ti = cs * b.y + sn * b.x;
        s[i1] = make_float2(a.x + tr, a.y + ti);
        s[i2] = make_float2(a.x - tr, a.y - ti);
        __syncthreads();
    }
}

// ---------------- SOA FFT helpers (for 8-col kernel) ----------------
__device__ __forceinline__ void fft_dif_soa(float* re, float* im, const float2* tw, int t) {
    #pragma unroll
    for (int st = 7; st >= 0; --st) {
        int half = 1 << st;
        int j  = t & (half - 1);
        int i1 = ((t >> st) << (st + 1)) + j;
        int i2 = i1 + half;
        float ar = re[i1], ai = im[i1], br = re[i2], bi = im[i2];
        float2 w = tw[j << (7 - st)];
        float dr = ar - br, di = ai - bi;
        re[i1] = ar + br;  im[i1] = ai + bi;
        re[i2] = w.x * dr - w.y * di;
        im[i2] = w.x * di + w.y * dr;
        __syncthreads();
    }
}

__device__ __forceinline__ void fft_dit_soa(float* re, float* im, const float2* tw, int t) {
    #pragma unroll
    for (int st = 0; st < 8; ++st) {
        int half = 1 << st;
        int j  = t & (half - 1);
        int i1 = ((t >> st) << (st + 1)) + j;
        int i2 = i1 + half;
        float ar = re[i1], ai = im[i1], br = re[i2], bi = im[i2];
        float2 w = tw[j << (7 - st)];
        float cs = w.x, sn = -w.y;
        float tr = cs * br - sn * bi;
        float ti = cs * bi + sn * br;
        re[i1] = ar + tr;  im[i1] = ai + ti;
        re[i2] = ar - tr;  im[i2] = ai - ti;
        __syncthreads();
    }
}

__device__ __forceinline__ void init_tw(float2* tw, int tid) {
    if (tid < 128) {
        float sn, cs;
        sincosf(-6.283185307179586f * (float)tid * (1.0f / 256.0f), &sn, &cs);
        tw[tid] = make_float2(cs, sn);
    }
}

// ---------------- Pass A: fused 5x5 blur + forward row FFT ----------------
__global__ __launch_bounds__(256) void fft_rows_fwd_blur_kernel(const float* __restrict__ img,
                                                                float2* __restrict__ freq)
{
    __shared__ float2 s[2][NBOX];
    __shared__ float  sb[2][NBOX];
    __shared__ float2 tw[128];
    int tid = threadIdx.x;
    int tx = tid & 127, ty = tid >> 7;
    init_tw(tw, tid);
    int row = blockIdx.x * 2 + ty;     // 0 .. B*N-1
    int b = row >> 8, y = row & (NBOX - 1);
    const float* ib = img + ((size_t)b << 16);
    const float gw[5] = {0.0544886845f, 0.2442013420f, 0.4026199469f,
                         0.2442013420f, 0.0544886845f};
    // vertical 5-tap (zero-padded)
    float acc0 = 0.f, acc1 = 0.f;
    #pragma unroll
    for (int dy = -2; dy <= 2; ++dy) {
        int yy = y + dy;
        if ((unsigned)yy < (unsigned)NBOX) {
            const float* rp = ib + yy * NBOX;
            acc0 += gw[dy + 2] * rp[tx];
            acc1 += gw[dy + 2] * rp[tx + 128];
        }
    }
    sb[ty][tx] = acc0;  sb[ty][tx + 128] = acc1;
    __syncthreads();
    // horizontal 5-tap (zero-padded)
    float r0 = 0.f, r1 = 0.f;
    #pragma unroll
    for (int dx = -2; dx <= 2; ++dx) {
        int x0 = tx + dx, x1 = tx + 128 + dx;
        if ((unsigned)x0 < (unsigned)NBOX) r0 += gw[dx + 2] * sb[ty][x0];
        if ((unsigned)x1 < (unsigned)NBOX) r1 += gw[dx + 2] * sb[ty][x1];
    }
    s[ty][tx]       = make_float2(r0, 0.f);
    s[ty][tx + 128] = make_float2(r1, 0.f);
    __syncthreads();
    fft_dif_t(s[ty], tw, tx);
    float2* op = freq + (size_t)row * NBOX;
    op[tx]       = s[ty][tx];
    op[tx + 128] = s[ty][tx + 128];
}

// ---------------- Pass B: 8-column fused fwd-FFT * ctf * inv-FFT ----------------
__global__ __launch_bounds__(1024) void fft_cols_ctf8_kernel(float2* __restrict__ freq,
                                                             const float* __restrict__ ctf)
{
    __shared__ float  s_re[8][257];
    __shared__ float  s_im[8][257];
    __shared__ float2 tw[128];
    int tid = threadIdx.x;
    init_tw(tw, tid);
    int col = tid & 7, j = tid >> 3;          // j in 0..127
    int blk = blockIdx.x;
    int b = blk >> 5;
    int x = ((blk & 31) << 3) + col;          // storage x
    float2* base = freq + ((size_t)b << 16) + x;

    float2 v0 = base[(size_t)j * NBOX];
    float2 v1 = base[(size_t)(j + 128) * NBOX];
    s_re[col][j] = v0.x;        s_im[col][j] = v0.y;
    s_re[col][j + 128] = v1.x;  s_im[col][j + 128] = v1.y;
    __syncthreads();

    fft_dif_soa(s_re[col], s_im[col], tw, j);

    // storage index i holds y-freq rev8(i); this column holds x-freq rev8(x)
    const float* cb = ctf + ((size_t)b << 16) + rev8(x);
    float c0 = cb[rev8(j) * NBOX];
    float c1 = cb[rev8(j + 128) * NBOX];
    s_re[col][j] *= c0;        s_im[col][j] *= c0;
    s_re[col][j + 128] *= c1;  s_im[col][j + 128] *= c1;
    __syncthreads();

    fft_dit_soa(s_re[col], s_im[col], tw, j);

    const float inv = 1.0f / 256.0f;
    base[(size_t)j * NBOX]         = make_float2(s_re[col][j] * inv, s_im[col][j] * inv);
    base[(size_t)(j + 128) * NBOX] = make_float2(s_re[col][j + 128] * inv, s_im[col][j + 128] * inv);
}

// ---------------- Pass C: inverse row FFT -> real output ----------------
__global__ __launch_bounds__(256) void fft_rows_inv_kernel(const float2* __restrict__ freq,
                                                           float* __restrict__ out)
{
    __shared__ float2 s[2][NBOX];
    __shared__ float2 tw[128];
    int tid = threadIdx.x;
    int tx = tid & 127, ty = tid >> 7;
    init_tw(tw, tid);
    int row = blockIdx.x * 2 + ty;
    const float2* rp = freq + (size_t)row * NBOX;
    s[ty][tx]       = rp[tx];
    s[ty][tx + 128] = rp[tx + 128];
    __syncthreads();
    fft_dit_t(s[ty], tw, tx);
    const float inv = 1.0f / 256.0f;
    out[(size_t)row * NBOX + tx]       = s[ty][tx].x * inv;
    out[(size_t)row * NBOX + tx + 128] = s[ty][tx + 128].x * inv;
}

extern "C" void kernel_launch(void* const* d_in, const int* in_sizes, int n_in,
                              void* d_out, int out_size, void* d_ws, size_t ws_size,
                              hipStream_t stream)
{
    (void)in_sizes; (void)n_in; (void)out_size;
    const float* z_x     = (const float*)d_in[0];
    const float* z_y     = (const float*)d_in[1];
    const float* z_z     = (const float*)d_in[2];
    const float* Zb      = (const float*)d_in[3];
    const float* coords  = (const float*)d_in[4];
    const float* weights = (const float*)d_in[5];
    const float* R       = (const float*)d_in[6];
    const float* shifts  = (const float*)d_in[7];
    const float* ctf     = (const float*)d_in[8];
    float* out = (float*)d_out;

    const size_t NELEM = (size_t)NIMG * NBOX * NBOX;           // 2,097,152
    const size_t NPAIR = (size_t)NIMG * NPTS;                  // 9.6 M
    float*  img   = (float*)d_ws;                              // 8 MB
    float2* freq  = (float2*)(img + NELEM);                    // 16 MB
    float2* pairs = freq + NELEM;                              // 76.8 MB
    const size_t required = NELEM * 4 + NELEM * 8 + NPAIR * 8;

    zero_kernel<<<(int)(NELEM / 4 + 255) / 256, 256, 0, stream>>>((float4*)img, (int)(NELEM / 4));

    if (ws_size >= required) {
        project_kernel<<<(NPTS + 255) / 256, 256, 0, stream>>>(z_x, z_y, z_z, Zb, coords,
                                                               R, shifts, pairs);
        splat2_kernel<<<NGROUP * BANDS, 256, 0, stream>>>(pairs, weights, img);
    } else {
        splat_kernel<<<(NPTS + 255) / 256, 256, 0, stream>>>(z_x, z_y, z_z, Zb, coords,
                                                             weights, R, shifts, img);
    }

    // fused blur + row FFT
    fft_rows_fwd_blur_kernel<<<NIMG * NBOX / 2, 256, 0, stream>>>(img, freq);
    // 8-column fused col-FFT * ctf * inv-col-FFT
    fft_cols_ctf8_kernel<<<NIMG * 32, 1024, 0, stream>>>(freq, ctf);
    // inverse row FFT -> real out
    fft_rows_inv_kernel<<<NIMG * NBOX / 2, 256, 0, stream>>>(freq, out);
}